// Round 1
// baseline (2152.804 us; speedup 1.0000x reference)
//
#include <hip/hip_runtime.h>
#include <cstddef>

#define NN 50000
#define NE 800000
#define D 128
#define BN_EPS 1e-5f
#define LDSTR 132   // padded LDS row stride (floats)

// ---------------------------------------------------------------------------
// Tiled 2-layer MLP over a 64-row tile: out = (relu(X@W1+b1))@W2 + b2
// X rows staged in LDS; W streamed from global (L1/L2 resident, uniform per
// half-wave). Each thread: 8 rows x 4 cols accumulator.
// Also accumulates per-column sum / sumsq partials for BatchNorm into stats.
// ---------------------------------------------------------------------------

__global__ __launch_bounds__(256) void mlp_edge_kernel(
    const float* __restrict__ h, const float* __restrict__ e,
    const int* __restrict__ src, const int* __restrict__ dst,
    const float* __restrict__ W1, const float* __restrict__ b1,
    const float* __restrict__ W2, const float* __restrict__ b2,
    float* __restrict__ x2out, float* __restrict__ stats)
{
    __shared__ float S[64 * LDSTR];
    const int tid = threadIdx.x;
    const int cg  = tid & 31;      // column group -> cols 4cg..4cg+3
    const int rg  = tid >> 5;      // row group    -> rows 8rg..8rg+7
    const int c0  = cg * 4;
    const long r0 = (long)blockIdx.x * 64;

    // ---- stage me = h[src] + h[dst] + e into LDS (row-major, padded) ----
#pragma unroll
    for (int p = 0; p < 8; ++p) {
        const int r = p * 8 + rg;
        const long row = r0 + r;
        const int sN = src[row];
        const int dN = dst[row];
        const float4 ev = *(const float4*)(e + (size_t)row * D + c0);
        const float4 hs = *(const float4*)(h + (size_t)sN * D + c0);
        const float4 hd = *(const float4*)(h + (size_t)dN * D + c0);
        float4 v;
        v.x = ev.x + hs.x + hd.x;
        v.y = ev.y + hs.y + hd.y;
        v.z = ev.z + hs.z + hd.z;
        v.w = ev.w + hs.w + hd.w;
        *(float4*)(S + r * LDSTR + c0) = v;
    }
    __syncthreads();

    // ---- GEMM1: acc = X @ W1 ----
    float acc[8][4];
#pragma unroll
    for (int i = 0; i < 8; ++i)
#pragma unroll
        for (int j = 0; j < 4; ++j) acc[i][j] = 0.f;

#pragma unroll 4
    for (int k = 0; k < D; ++k) {
        const float4 w = *(const float4*)(W1 + k * D + c0);
#pragma unroll
        for (int i = 0; i < 8; ++i) {
            const float x = S[(rg * 8 + i) * LDSTR + k];  // wave-broadcast
            acc[i][0] = fmaf(x, w.x, acc[i][0]);
            acc[i][1] = fmaf(x, w.y, acc[i][1]);
            acc[i][2] = fmaf(x, w.z, acc[i][2]);
            acc[i][3] = fmaf(x, w.w, acc[i][3]);
        }
    }

    const float4 bv1 = *(const float4*)(b1 + c0);
    __syncthreads();  // all GEMM1 reads of S done
#pragma unroll
    for (int i = 0; i < 8; ++i) {
        float4 v;
        v.x = fmaxf(acc[i][0] + bv1.x, 0.f);
        v.y = fmaxf(acc[i][1] + bv1.y, 0.f);
        v.z = fmaxf(acc[i][2] + bv1.z, 0.f);
        v.w = fmaxf(acc[i][3] + bv1.w, 0.f);
        *(float4*)(S + (rg * 8 + i) * LDSTR + c0) = v;
    }
    __syncthreads();

    // ---- GEMM2: a2 = Y @ W2 ----
    float a2[8][4];
#pragma unroll
    for (int i = 0; i < 8; ++i)
#pragma unroll
        for (int j = 0; j < 4; ++j) a2[i][j] = 0.f;

#pragma unroll 4
    for (int k = 0; k < D; ++k) {
        const float4 w = *(const float4*)(W2 + k * D + c0);
#pragma unroll
        for (int i = 0; i < 8; ++i) {
            const float x = S[(rg * 8 + i) * LDSTR + k];
            a2[i][0] = fmaf(x, w.x, a2[i][0]);
            a2[i][1] = fmaf(x, w.y, a2[i][1]);
            a2[i][2] = fmaf(x, w.z, a2[i][2]);
            a2[i][3] = fmaf(x, w.w, a2[i][3]);
        }
    }

    const float4 bv2 = *(const float4*)(b2 + c0);
    float ts[4] = {0.f, 0.f, 0.f, 0.f};
    float tq[4] = {0.f, 0.f, 0.f, 0.f};
#pragma unroll
    for (int i = 0; i < 8; ++i) {
        float4 v;
        v.x = a2[i][0] + bv2.x;
        v.y = a2[i][1] + bv2.y;
        v.z = a2[i][2] + bv2.z;
        v.w = a2[i][3] + bv2.w;
        *(float4*)(x2out + (size_t)(r0 + rg * 8 + i) * D + c0) = v;
        ts[0] += v.x; ts[1] += v.y; ts[2] += v.z; ts[3] += v.w;
        tq[0] += v.x * v.x; tq[1] += v.y * v.y;
        tq[2] += v.z * v.z; tq[3] += v.w * v.w;
    }

    // ---- per-block column reduction for BN stats ----
    __syncthreads();  // all GEMM2 reads of S done
    *(float4*)(S + rg * 128 + c0)        = make_float4(ts[0], ts[1], ts[2], ts[3]);
    *(float4*)(S + 1024 + rg * 128 + c0) = make_float4(tq[0], tq[1], tq[2], tq[3]);
    __syncthreads();
    if (tid < 128) {
        float s = 0.f, q = 0.f;
#pragma unroll
        for (int g = 0; g < 8; ++g) {
            s += S[g * 128 + tid];
            q += S[1024 + g * 128 + tid];
        }
        unsafeAtomicAdd(&stats[tid], s);
        unsafeAtomicAdd(&stats[128 + tid], q);
    }
}

__global__ __launch_bounds__(256) void mlp_node_kernel(
    const float* __restrict__ h, const float* __restrict__ agg,
    const float* __restrict__ W1, const float* __restrict__ b1,
    const float* __restrict__ W2, const float* __restrict__ b2,
    float* __restrict__ x2out, float* __restrict__ stats)
{
    __shared__ float S[64 * LDSTR];
    const int tid = threadIdx.x;
    const int cg  = tid & 31;
    const int rg  = tid >> 5;
    const int c0  = cg * 4;
    const long r0 = (long)blockIdx.x * 64;

#pragma unroll
    for (int p = 0; p < 8; ++p) {
        const int r = p * 8 + rg;
        const long row = r0 + r;
        float4 v = make_float4(0.f, 0.f, 0.f, 0.f);
        if (row < NN) {
            const float4 hv = *(const float4*)(h + (size_t)row * D + c0);
            const float4 av = *(const float4*)(agg + (size_t)row * D + c0);
            v.x = hv.x + av.x; v.y = hv.y + av.y;
            v.z = hv.z + av.z; v.w = hv.w + av.w;
        }
        *(float4*)(S + r * LDSTR + c0) = v;
    }
    __syncthreads();

    float acc[8][4];
#pragma unroll
    for (int i = 0; i < 8; ++i)
#pragma unroll
        for (int j = 0; j < 4; ++j) acc[i][j] = 0.f;

#pragma unroll 4
    for (int k = 0; k < D; ++k) {
        const float4 w = *(const float4*)(W1 + k * D + c0);
#pragma unroll
        for (int i = 0; i < 8; ++i) {
            const float x = S[(rg * 8 + i) * LDSTR + k];
            acc[i][0] = fmaf(x, w.x, acc[i][0]);
            acc[i][1] = fmaf(x, w.y, acc[i][1]);
            acc[i][2] = fmaf(x, w.z, acc[i][2]);
            acc[i][3] = fmaf(x, w.w, acc[i][3]);
        }
    }

    const float4 bv1 = *(const float4*)(b1 + c0);
    __syncthreads();
#pragma unroll
    for (int i = 0; i < 8; ++i) {
        float4 v;
        v.x = fmaxf(acc[i][0] + bv1.x, 0.f);
        v.y = fmaxf(acc[i][1] + bv1.y, 0.f);
        v.z = fmaxf(acc[i][2] + bv1.z, 0.f);
        v.w = fmaxf(acc[i][3] + bv1.w, 0.f);
        *(float4*)(S + (rg * 8 + i) * LDSTR + c0) = v;
    }
    __syncthreads();

    float a2[8][4];
#pragma unroll
    for (int i = 0; i < 8; ++i)
#pragma unroll
        for (int j = 0; j < 4; ++j) a2[i][j] = 0.f;

#pragma unroll 4
    for (int k = 0; k < D; ++k) {
        const float4 w = *(const float4*)(W2 + k * D + c0);
#pragma unroll
        for (int i = 0; i < 8; ++i) {
            const float x = S[(rg * 8 + i) * LDSTR + k];
            a2[i][0] = fmaf(x, w.x, a2[i][0]);
            a2[i][1] = fmaf(x, w.y, a2[i][1]);
            a2[i][2] = fmaf(x, w.z, a2[i][2]);
            a2[i][3] = fmaf(x, w.w, a2[i][3]);
        }
    }

    const float4 bv2 = *(const float4*)(b2 + c0);
    float ts[4] = {0.f, 0.f, 0.f, 0.f};
    float tq[4] = {0.f, 0.f, 0.f, 0.f};
#pragma unroll
    for (int i = 0; i < 8; ++i) {
        const long row = r0 + rg * 8 + i;
        if (row < NN) {
            float4 v;
            v.x = a2[i][0] + bv2.x;
            v.y = a2[i][1] + bv2.y;
            v.z = a2[i][2] + bv2.z;
            v.w = a2[i][3] + bv2.w;
            *(float4*)(x2out + (size_t)row * D + c0) = v;
            ts[0] += v.x; ts[1] += v.y; ts[2] += v.z; ts[3] += v.w;
            tq[0] += v.x * v.x; tq[1] += v.y * v.y;
            tq[2] += v.z * v.z; tq[3] += v.w * v.w;
        }
    }

    __syncthreads();
    *(float4*)(S + rg * 128 + c0)        = make_float4(ts[0], ts[1], ts[2], ts[3]);
    *(float4*)(S + 1024 + rg * 128 + c0) = make_float4(tq[0], tq[1], tq[2], tq[3]);
    __syncthreads();
    if (tid < 128) {
        float s = 0.f, q = 0.f;
#pragma unroll
        for (int g = 0; g < 8; ++g) {
            s += S[g * 128 + tid];
            q += S[1024 + g * 128 + tid];
        }
        unsafeAtomicAdd(&stats[tid], s);
        unsafeAtomicAdd(&stats[128 + tid], q);
    }
}

// stats layout: [0:128) sum, [128:256) sumsq, [256:384) scale, [384:512) shift
__global__ void bn_finalize_kernel(float* __restrict__ stats,
                                   const float* __restrict__ gamma,
                                   const float* __restrict__ beta,
                                   float inv_count)
{
    const int c = threadIdx.x;
    if (c < D) {
        const float mu  = stats[c] * inv_count;
        const float var = stats[128 + c] * inv_count - mu * mu;
        const float sc  = rsqrtf(var + BN_EPS) * gamma[c];
        stats[256 + c] = sc;
        stats[384 + c] = beta[c] - mu * sc;
    }
}

// e_new = x2*scale + shift + e (in-place over x2 in d_out), scatter into agg
__global__ __launch_bounds__(256) void edge_apply_kernel(
    const float* __restrict__ e, const int* __restrict__ dst,
    const float* __restrict__ stats, float* __restrict__ eout,
    float* __restrict__ agg)
{
    const int gid  = blockIdx.x * 256 + threadIdx.x;
    const int edge = gid >> 5;
    const int c0   = (gid & 31) * 4;
    const size_t base = (size_t)edge * D + c0;

    const float4 sc = *(const float4*)(stats + 256 + c0);
    const float4 sh = *(const float4*)(stats + 384 + c0);
    const float4 x  = *(const float4*)(eout + base);
    const float4 ev = *(const float4*)(e + base);
    float4 v;
    v.x = fmaf(x.x, sc.x, sh.x) + ev.x;
    v.y = fmaf(x.y, sc.y, sh.y) + ev.y;
    v.z = fmaf(x.z, sc.z, sh.z) + ev.z;
    v.w = fmaf(x.w, sc.w, sh.w) + ev.w;
    *(float4*)(eout + base) = v;

    const int dn = dst[edge];
    float* a = agg + (size_t)dn * D + c0;
    unsafeAtomicAdd(a + 0, v.x);
    unsafeAtomicAdd(a + 1, v.y);
    unsafeAtomicAdd(a + 2, v.z);
    unsafeAtomicAdd(a + 3, v.w);
}

// h_new = y2*scale + shift + h (in-place over y2 in d_out)
__global__ __launch_bounds__(256) void node_apply_kernel(
    const float* __restrict__ h, const float* __restrict__ stats,
    float* __restrict__ hout)
{
    const int gid = blockIdx.x * 256 + threadIdx.x;
    const int c0  = (gid & 31) * 4;
    const size_t base = (size_t)(gid >> 5) * D + c0;

    const float4 sc = *(const float4*)(stats + 256 + c0);
    const float4 sh = *(const float4*)(stats + 384 + c0);
    const float4 x  = *(const float4*)(hout + base);
    const float4 hv = *(const float4*)(h + base);
    float4 v;
    v.x = fmaf(x.x, sc.x, sh.x) + hv.x;
    v.y = fmaf(x.y, sc.y, sh.y) + hv.y;
    v.z = fmaf(x.z, sc.z, sh.z) + hv.z;
    v.w = fmaf(x.w, sc.w, sh.w) + hv.w;
    *(float4*)(hout + base) = v;
}

extern "C" void kernel_launch(void* const* d_in, const int* in_sizes, int n_in,
                              void* d_out, int out_size, void* d_ws, size_t ws_size,
                              hipStream_t stream)
{
    const float* h   = (const float*)d_in[0];
    const float* e   = (const float*)d_in[1];
    const int*   src = (const int*)d_in[2];
    const int*   dst = (const int*)d_in[3];
    const float* Wa1 = (const float*)d_in[4];
    const float* ba1 = (const float*)d_in[5];
    const float* Wa2 = (const float*)d_in[6];
    const float* ba2 = (const float*)d_in[7];
    const float* Wb1 = (const float*)d_in[8];
    const float* bb1 = (const float*)d_in[9];
    const float* Wb2 = (const float*)d_in[10];
    const float* bb2 = (const float*)d_in[11];
    const float* ga  = (const float*)d_in[12];
    const float* bea = (const float*)d_in[13];
    const float* gb  = (const float*)d_in[14];
    const float* beb = (const float*)d_in[15];

    float* out  = (float*)d_out;
    float* hnew = out;                      // NN*D
    float* enew = out + (size_t)NN * D;     // NE*D

    float* ws     = (float*)d_ws;
    float* estats = ws;                     // 512 floats
    float* nstats = ws + 512;               // 512 floats
    float* agg    = ws + 1024;              // NN*D floats

    // zero BN stats + agg accumulator (atomic targets) every call
    hipMemsetAsync(d_ws, 0, (size_t)(1024 + (size_t)NN * D) * sizeof(float), stream);

    // ---- bond (edge) path ----
    mlp_edge_kernel<<<NE / 64, 256, 0, stream>>>(h, e, src, dst,
                                                 Wb1, bb1, Wb2, bb2,
                                                 enew /*x2 scratch*/, estats);
    bn_finalize_kernel<<<1, 128, 0, stream>>>(estats, gb, beb, 1.0f / NE);
    edge_apply_kernel<<<(NE * 32) / 256, 256, 0, stream>>>(e, dst, estats, enew, agg);

    // ---- atom (node) path ----
    mlp_node_kernel<<<(NN + 63) / 64, 256, 0, stream>>>(h, agg,
                                                        Wa1, ba1, Wa2, ba2,
                                                        hnew /*y2 scratch*/, nstats);
    bn_finalize_kernel<<<1, 128, 0, stream>>>(nstats, ga, bea, 1.0f / NN);
    node_apply_kernel<<<(NN * 32) / 256, 256, 0, stream>>>(h, nstats, hnew);
}

// Round 2
// 1310.594 us; speedup vs baseline: 1.6426x; 1.6426x over previous
//
#include <hip/hip_runtime.h>
#include <cstddef>

#define NN 50000
#define NE 800000
#define D 128
#define BN_EPS 1e-5f
#define LDSTR 132   // padded LDS row stride (floats)

// ---------------------------------------------------------------------------
// Tiled 2-layer MLP over a 64-row tile: out = (relu(X@W1+b1))@W2 + b2
// X rows staged in LDS; W streamed from global (L1/L2 resident, uniform per
// half-wave). Each thread: 8 rows x 4 cols accumulator.
// Also accumulates per-column sum / sumsq partials for BatchNorm into stats.
// ---------------------------------------------------------------------------

__global__ __launch_bounds__(256) void mlp_edge_kernel(
    const float* __restrict__ h, const float* __restrict__ e,
    const int* __restrict__ src, const int* __restrict__ dst,
    const float* __restrict__ W1, const float* __restrict__ b1,
    const float* __restrict__ W2, const float* __restrict__ b2,
    float* __restrict__ x2out, float* __restrict__ stats)
{
    __shared__ float S[64 * LDSTR];
    const int tid = threadIdx.x;
    const int cg  = tid & 31;      // column group -> cols 4cg..4cg+3
    const int rg  = tid >> 5;      // row group    -> rows 8rg..8rg+7
    const int c0  = cg * 4;
    const long r0 = (long)blockIdx.x * 64;

    // ---- stage me = h[src] + h[dst] + e into LDS (row-major, padded) ----
#pragma unroll
    for (int p = 0; p < 8; ++p) {
        const int r = p * 8 + rg;
        const long row = r0 + r;
        const int sN = src[row];
        const int dN = dst[row];
        const float4 ev = *(const float4*)(e + (size_t)row * D + c0);
        const float4 hs = *(const float4*)(h + (size_t)sN * D + c0);
        const float4 hd = *(const float4*)(h + (size_t)dN * D + c0);
        float4 v;
        v.x = ev.x + hs.x + hd.x;
        v.y = ev.y + hs.y + hd.y;
        v.z = ev.z + hs.z + hd.z;
        v.w = ev.w + hs.w + hd.w;
        *(float4*)(S + r * LDSTR + c0) = v;
    }
    __syncthreads();

    // ---- GEMM1: acc = X @ W1 ----
    float acc[8][4];
#pragma unroll
    for (int i = 0; i < 8; ++i)
#pragma unroll
        for (int j = 0; j < 4; ++j) acc[i][j] = 0.f;

#pragma unroll 4
    for (int k = 0; k < D; ++k) {
        const float4 w = *(const float4*)(W1 + k * D + c0);
#pragma unroll
        for (int i = 0; i < 8; ++i) {
            const float x = S[(rg * 8 + i) * LDSTR + k];  // wave-broadcast
            acc[i][0] = fmaf(x, w.x, acc[i][0]);
            acc[i][1] = fmaf(x, w.y, acc[i][1]);
            acc[i][2] = fmaf(x, w.z, acc[i][2]);
            acc[i][3] = fmaf(x, w.w, acc[i][3]);
        }
    }

    const float4 bv1 = *(const float4*)(b1 + c0);
    __syncthreads();  // all GEMM1 reads of S done
#pragma unroll
    for (int i = 0; i < 8; ++i) {
        float4 v;
        v.x = fmaxf(acc[i][0] + bv1.x, 0.f);
        v.y = fmaxf(acc[i][1] + bv1.y, 0.f);
        v.z = fmaxf(acc[i][2] + bv1.z, 0.f);
        v.w = fmaxf(acc[i][3] + bv1.w, 0.f);
        *(float4*)(S + (rg * 8 + i) * LDSTR + c0) = v;
    }
    __syncthreads();

    // ---- GEMM2: a2 = Y @ W2 ----
    float a2[8][4];
#pragma unroll
    for (int i = 0; i < 8; ++i)
#pragma unroll
        for (int j = 0; j < 4; ++j) a2[i][j] = 0.f;

#pragma unroll 4
    for (int k = 0; k < D; ++k) {
        const float4 w = *(const float4*)(W2 + k * D + c0);
#pragma unroll
        for (int i = 0; i < 8; ++i) {
            const float x = S[(rg * 8 + i) * LDSTR + k];
            a2[i][0] = fmaf(x, w.x, a2[i][0]);
            a2[i][1] = fmaf(x, w.y, a2[i][1]);
            a2[i][2] = fmaf(x, w.z, a2[i][2]);
            a2[i][3] = fmaf(x, w.w, a2[i][3]);
        }
    }

    const float4 bv2 = *(const float4*)(b2 + c0);
    float ts[4] = {0.f, 0.f, 0.f, 0.f};
    float tq[4] = {0.f, 0.f, 0.f, 0.f};
#pragma unroll
    for (int i = 0; i < 8; ++i) {
        float4 v;
        v.x = a2[i][0] + bv2.x;
        v.y = a2[i][1] + bv2.y;
        v.z = a2[i][2] + bv2.z;
        v.w = a2[i][3] + bv2.w;
        *(float4*)(x2out + (size_t)(r0 + rg * 8 + i) * D + c0) = v;
        ts[0] += v.x; ts[1] += v.y; ts[2] += v.z; ts[3] += v.w;
        tq[0] += v.x * v.x; tq[1] += v.y * v.y;
        tq[2] += v.z * v.z; tq[3] += v.w * v.w;
    }

    // ---- per-block column reduction for BN stats ----
    __syncthreads();  // all GEMM2 reads of S done
    *(float4*)(S + rg * 128 + c0)        = make_float4(ts[0], ts[1], ts[2], ts[3]);
    *(float4*)(S + 1024 + rg * 128 + c0) = make_float4(tq[0], tq[1], tq[2], tq[3]);
    __syncthreads();
    if (tid < 128) {
        float s = 0.f, q = 0.f;
#pragma unroll
        for (int g = 0; g < 8; ++g) {
            s += S[g * 128 + tid];
            q += S[1024 + g * 128 + tid];
        }
        unsafeAtomicAdd(&stats[tid], s);
        unsafeAtomicAdd(&stats[128 + tid], q);
    }
}

__global__ __launch_bounds__(256) void mlp_node_kernel(
    const float* __restrict__ h, const float* __restrict__ agg,
    const float* __restrict__ W1, const float* __restrict__ b1,
    const float* __restrict__ W2, const float* __restrict__ b2,
    float* __restrict__ x2out, float* __restrict__ stats)
{
    __shared__ float S[64 * LDSTR];
    const int tid = threadIdx.x;
    const int cg  = tid & 31;
    const int rg  = tid >> 5;
    const int c0  = cg * 4;
    const long r0 = (long)blockIdx.x * 64;

#pragma unroll
    for (int p = 0; p < 8; ++p) {
        const int r = p * 8 + rg;
        const long row = r0 + r;
        float4 v = make_float4(0.f, 0.f, 0.f, 0.f);
        if (row < NN) {
            const float4 hv = *(const float4*)(h + (size_t)row * D + c0);
            const float4 av = *(const float4*)(agg + (size_t)row * D + c0);
            v.x = hv.x + av.x; v.y = hv.y + av.y;
            v.z = hv.z + av.z; v.w = hv.w + av.w;
        }
        *(float4*)(S + r * LDSTR + c0) = v;
    }
    __syncthreads();

    float acc[8][4];
#pragma unroll
    for (int i = 0; i < 8; ++i)
#pragma unroll
        for (int j = 0; j < 4; ++j) acc[i][j] = 0.f;

#pragma unroll 4
    for (int k = 0; k < D; ++k) {
        const float4 w = *(const float4*)(W1 + k * D + c0);
#pragma unroll
        for (int i = 0; i < 8; ++i) {
            const float x = S[(rg * 8 + i) * LDSTR + k];
            acc[i][0] = fmaf(x, w.x, acc[i][0]);
            acc[i][1] = fmaf(x, w.y, acc[i][1]);
            acc[i][2] = fmaf(x, w.z, acc[i][2]);
            acc[i][3] = fmaf(x, w.w, acc[i][3]);
        }
    }

    const float4 bv1 = *(const float4*)(b1 + c0);
    __syncthreads();
#pragma unroll
    for (int i = 0; i < 8; ++i) {
        float4 v;
        v.x = fmaxf(acc[i][0] + bv1.x, 0.f);
        v.y = fmaxf(acc[i][1] + bv1.y, 0.f);
        v.z = fmaxf(acc[i][2] + bv1.z, 0.f);
        v.w = fmaxf(acc[i][3] + bv1.w, 0.f);
        *(float4*)(S + (rg * 8 + i) * LDSTR + c0) = v;
    }
    __syncthreads();

    float a2[8][4];
#pragma unroll
    for (int i = 0; i < 8; ++i)
#pragma unroll
        for (int j = 0; j < 4; ++j) a2[i][j] = 0.f;

#pragma unroll 4
    for (int k = 0; k < D; ++k) {
        const float4 w = *(const float4*)(W2 + k * D + c0);
#pragma unroll
        for (int i = 0; i < 8; ++i) {
            const float x = S[(rg * 8 + i) * LDSTR + k];
            a2[i][0] = fmaf(x, w.x, a2[i][0]);
            a2[i][1] = fmaf(x, w.y, a2[i][1]);
            a2[i][2] = fmaf(x, w.z, a2[i][2]);
            a2[i][3] = fmaf(x, w.w, a2[i][3]);
        }
    }

    const float4 bv2 = *(const float4*)(b2 + c0);
    float ts[4] = {0.f, 0.f, 0.f, 0.f};
    float tq[4] = {0.f, 0.f, 0.f, 0.f};
#pragma unroll
    for (int i = 0; i < 8; ++i) {
        const long row = r0 + rg * 8 + i;
        if (row < NN) {
            float4 v;
            v.x = a2[i][0] + bv2.x;
            v.y = a2[i][1] + bv2.y;
            v.z = a2[i][2] + bv2.z;
            v.w = a2[i][3] + bv2.w;
            *(float4*)(x2out + (size_t)row * D + c0) = v;
            ts[0] += v.x; ts[1] += v.y; ts[2] += v.z; ts[3] += v.w;
            tq[0] += v.x * v.x; tq[1] += v.y * v.y;
            tq[2] += v.z * v.z; tq[3] += v.w * v.w;
        }
    }

    __syncthreads();
    *(float4*)(S + rg * 128 + c0)        = make_float4(ts[0], ts[1], ts[2], ts[3]);
    *(float4*)(S + 1024 + rg * 128 + c0) = make_float4(tq[0], tq[1], tq[2], tq[3]);
    __syncthreads();
    if (tid < 128) {
        float s = 0.f, q = 0.f;
#pragma unroll
        for (int g = 0; g < 8; ++g) {
            s += S[g * 128 + tid];
            q += S[1024 + g * 128 + tid];
        }
        unsafeAtomicAdd(&stats[tid], s);
        unsafeAtomicAdd(&stats[128 + tid], q);
    }
}

// stats layout: [0:128) sum, [128:256) sumsq, [256:384) scale, [384:512) shift
__global__ void bn_finalize_kernel(float* __restrict__ stats,
                                   const float* __restrict__ gamma,
                                   const float* __restrict__ beta,
                                   float inv_count)
{
    const int c = threadIdx.x;
    if (c < D) {
        const float mu  = stats[c] * inv_count;
        const float var = stats[128 + c] * inv_count - mu * mu;
        const float sc  = rsqrtf(var + BN_EPS) * gamma[c];
        stats[256 + c] = sc;
        stats[384 + c] = beta[c] - mu * sc;
    }
}

// ---- CSR build: histogram of dst ----
__global__ __launch_bounds__(256) void hist_kernel(
    const int* __restrict__ dst, int* __restrict__ cnt)
{
    const int i = blockIdx.x * 256 + threadIdx.x;
    if (i < NE) atomicAdd(&cnt[dst[i]], 1);
}

// single-block exclusive scan of cnt[0..NN) -> off[0..NN]
__global__ __launch_bounds__(1024) void scan_kernel(
    const int* __restrict__ cnt, int* __restrict__ off)
{
    __shared__ int part[1024];
    const int t = threadIdx.x;
    const int SEG = (NN + 1023) / 1024;   // 49
    const int base = t * SEG;

    int s = 0;
    for (int i = 0; i < SEG; ++i) {
        const int idx = base + i;
        if (idx < NN) s += cnt[idx];
    }
    part[t] = s;
    __syncthreads();
    // Hillis-Steele inclusive scan
    for (int d = 1; d < 1024; d <<= 1) {
        int v = (t >= d) ? part[t - d] : 0;
        __syncthreads();
        part[t] += v;
        __syncthreads();
    }
    int run = (t > 0) ? part[t - 1] : 0;
    for (int i = 0; i < SEG; ++i) {
        const int idx = base + i;
        if (idx < NN) { off[idx] = run; run += cnt[idx]; }
    }
    if (t == 1023) off[NN] = part[1023];
}

// scatter edge ids into CSR slots; reuses cnt as down-counting cursor
__global__ __launch_bounds__(256) void csr_scatter_kernel(
    const int* __restrict__ dst, const int* __restrict__ off,
    int* __restrict__ cnt, int* __restrict__ csr)
{
    const int i = blockIdx.x * 256 + threadIdx.x;
    if (i < NE) {
        const int d = dst[i];
        const int p = atomicSub(&cnt[d], 1) - 1;   // unique slot within segment
        csr[off[d] + p] = i;
    }
}

// e_new = x2*scale + shift + e (in-place over x2 in d_out) — pure streaming
__global__ __launch_bounds__(256) void edge_apply_kernel(
    const float* __restrict__ e, const float* __restrict__ stats,
    float* __restrict__ eout)
{
    const int gid  = blockIdx.x * 256 + threadIdx.x;
    const int edge = gid >> 5;
    const int c0   = (gid & 31) * 4;
    const size_t base = (size_t)edge * D + c0;

    const float4 sc = *(const float4*)(stats + 256 + c0);
    const float4 sh = *(const float4*)(stats + 384 + c0);
    const float4 x  = *(const float4*)(eout + base);
    const float4 ev = *(const float4*)(e + base);
    float4 v;
    v.x = fmaf(x.x, sc.x, sh.x) + ev.x;
    v.y = fmaf(x.y, sc.y, sh.y) + ev.y;
    v.z = fmaf(x.z, sc.z, sh.z) + ev.z;
    v.w = fmaf(x.w, sc.w, sh.w) + ev.w;
    *(float4*)(eout + base) = v;
}

// agg[n] = sum of e_new rows incident to n (CSR gather, one wave per node)
__global__ __launch_bounds__(256) void agg_gather_kernel(
    const float* __restrict__ enew, const int* __restrict__ off,
    const int* __restrict__ csr, float* __restrict__ agg)
{
    const int node = blockIdx.x * 4 + (threadIdx.x >> 6);
    const int lane = threadIdx.x & 63;
    const int c0   = lane * 2;
    if (node >= NN) return;

    float2 acc = make_float2(0.f, 0.f);
    const int jb = off[node], je = off[node + 1];
    for (int j = jb; j < je; ++j) {
        const int eidx = csr[j];
        const float2 v = *(const float2*)(enew + (size_t)eidx * D + c0);
        acc.x += v.x;
        acc.y += v.y;
    }
    *(float2*)(agg + (size_t)node * D + c0) = acc;
}

// h_new = y2*scale + shift + h (in-place over y2 in d_out)
__global__ __launch_bounds__(256) void node_apply_kernel(
    const float* __restrict__ h, const float* __restrict__ stats,
    float* __restrict__ hout)
{
    const int gid = blockIdx.x * 256 + threadIdx.x;
    const int c0  = (gid & 31) * 4;
    const size_t base = (size_t)(gid >> 5) * D + c0;

    const float4 sc = *(const float4*)(stats + 256 + c0);
    const float4 sh = *(const float4*)(stats + 384 + c0);
    const float4 x  = *(const float4*)(hout + base);
    const float4 hv = *(const float4*)(h + base);
    float4 v;
    v.x = fmaf(x.x, sc.x, sh.x) + hv.x;
    v.y = fmaf(x.y, sc.y, sh.y) + hv.y;
    v.z = fmaf(x.z, sc.z, sh.z) + hv.z;
    v.w = fmaf(x.w, sc.w, sh.w) + hv.w;
    *(float4*)(hout + base) = v;
}

extern "C" void kernel_launch(void* const* d_in, const int* in_sizes, int n_in,
                              void* d_out, int out_size, void* d_ws, size_t ws_size,
                              hipStream_t stream)
{
    const float* h   = (const float*)d_in[0];
    const float* e   = (const float*)d_in[1];
    const int*   src = (const int*)d_in[2];
    const int*   dst = (const int*)d_in[3];
    const float* Wa1 = (const float*)d_in[4];
    const float* ba1 = (const float*)d_in[5];
    const float* Wa2 = (const float*)d_in[6];
    const float* ba2 = (const float*)d_in[7];
    const float* Wb1 = (const float*)d_in[8];
    const float* bb1 = (const float*)d_in[9];
    const float* Wb2 = (const float*)d_in[10];
    const float* bb2 = (const float*)d_in[11];
    const float* ga  = (const float*)d_in[12];
    const float* bea = (const float*)d_in[13];
    const float* gb  = (const float*)d_in[14];
    const float* beb = (const float*)d_in[15];

    float* out  = (float*)d_out;
    float* hnew = out;                      // NN*D
    float* enew = out + (size_t)NN * D;     // NE*D

    // ws layout (floats): estats[512] | nstats[512] | off[NN+1 ints] |
    //                     cnt[NN ints] | agg[NN*D] | csr[NE ints]
    float* ws     = (float*)d_ws;
    float* estats = ws;
    float* nstats = ws + 512;
    int*   ioff   = (int*)(ws + 1024);
    int*   icnt   = ioff + (NN + 1);
    float* agg    = (float*)(icnt + NN + 3);          // aligned (+3 pad)
    int*   icsr   = (int*)(agg + (size_t)NN * D);

    // zero stats + off + cnt + agg (everything before csr) in one memset
    const size_t zero_bytes = (size_t)((char*)icsr - (char*)d_ws);
    hipMemsetAsync(d_ws, 0, zero_bytes, stream);

    // ---- CSR build (independent of edge MLP; overlaps via stream order) ----
    hist_kernel<<<(NE + 255) / 256, 256, 0, stream>>>(dst, icnt);
    scan_kernel<<<1, 1024, 0, stream>>>(icnt, ioff);
    csr_scatter_kernel<<<(NE + 255) / 256, 256, 0, stream>>>(dst, ioff, icnt, icsr);

    // ---- bond (edge) path ----
    mlp_edge_kernel<<<NE / 64, 256, 0, stream>>>(h, e, src, dst,
                                                 Wb1, bb1, Wb2, bb2,
                                                 enew /*x2 scratch*/, estats);
    bn_finalize_kernel<<<1, 128, 0, stream>>>(estats, gb, beb, 1.0f / NE);
    edge_apply_kernel<<<(NE * 32) / 256, 256, 0, stream>>>(e, estats, enew);

    // ---- aggregate incident bonds per node (gather, no atomics) ----
    agg_gather_kernel<<<(NN + 3) / 4, 256, 0, stream>>>(enew, ioff, icsr, agg);

    // ---- atom (node) path ----
    mlp_node_kernel<<<(NN + 63) / 64, 256, 0, stream>>>(h, agg,
                                                        Wa1, ba1, Wa2, ba2,
                                                        hnew /*y2 scratch*/, nstats);
    bn_finalize_kernel<<<1, 128, 0, stream>>>(nstats, ga, bea, 1.0f / NN);
    node_apply_kernel<<<(NN * 32) / 256, 256, 0, stream>>>(h, nstats, hnew);
}

// Round 3
// 851.801 us; speedup vs baseline: 2.5274x; 1.5386x over previous
//
#include <hip/hip_runtime.h>
#include <cstddef>

#define NN 50000
#define NE 800000
#define D 128
#define BN_EPS 1e-5f

typedef __attribute__((ext_vector_type(8))) short bf16x8;     // 8 bf16 = 4 VGPR
typedef __attribute__((ext_vector_type(4))) float f32x4;
typedef __attribute__((ext_vector_type(4))) unsigned short us4;

__device__ __forceinline__ unsigned short f2bf(float x) {
    unsigned u = __float_as_uint(x);
    return (unsigned short)((u + 0x7fffu + ((u >> 16) & 1u)) >> 16);  // RNE
}
__device__ __forceinline__ float bf2f(unsigned short b) {
    return __uint_as_float(((unsigned)b) << 16);
}

// ---------------------------------------------------------------------------
// W prep: W[k][n] f32 -> fragment-linear bf16 Wt.
// Wt[ ((ct*4+ks)*64 + l)*8 + j ] = bf16( W[(32*ks + (l>>4)*8 + j)*128 + 16*ct + (l&15)] )
// so that wave-lane l's B-fragment for (col-tile ct, k-step ks) is one
// contiguous 16B global_load_dwordx4.
// ---------------------------------------------------------------------------
__global__ __launch_bounds__(256) void wprep_kernel(
    const float* __restrict__ W, unsigned short* __restrict__ Wt)
{
    const int idx = blockIdx.x * 256 + threadIdx.x;   // [0, 16384)
    const int j  = idx & 7;
    const int l  = (idx >> 3) & 63;
    const int ks = (idx >> 9) & 3;
    const int ct = (idx >> 11) & 7;
    const int n  = 16 * ct + (l & 15);
    const int k  = 32 * ks + ((l >> 4) << 3) + j;
    Wt[idx] = f2bf(W[k * 128 + n]);
}

// ---------------------------------------------------------------------------
// MFMA 2-layer MLP over a 64-row tile, split-bf16 (X = Xh + Xl, W plain bf16):
//   x2 = (relu(X@W1 + b1)) @ W2 + b2
// MODE 0 (edge): X = e[row] + h[src[row]] + h[dst[row]], rows = NE (exact).
// MODE 1 (node): X = h[row] + agg[row], rows = NN (guarded).
// W fragments live in 128 VGPRs; X/Y in XOR-swizzled bf16 LDS; a f32 LDS
// buffer (stride 132) transposes MFMA C-layout -> row-major for the Y
// restage and the final coalesced store + BN stats.
// ---------------------------------------------------------------------------
template<int MODE>
__global__ __launch_bounds__(256, 2) void mlp_mfma_kernel(
    const float* __restrict__ h, const float* __restrict__ e_or_agg,
    const int* __restrict__ src, const int* __restrict__ dst,
    const unsigned short* __restrict__ Wt1, const float* __restrict__ b1,
    const unsigned short* __restrict__ Wt2, const float* __restrict__ b2,
    float* __restrict__ x2out, float* __restrict__ stats)
{
    __shared__ __align__(16) unsigned short Xh[8192];   // 64 x 128 bf16 (swizzled)
    __shared__ __align__(16) unsigned short Xl[8192];
    __shared__ __align__(16) float OUTB[64 * 132];      // f32 transpose buffer

    const int tid  = threadIdx.x;
    const int lane = tid & 63;
    const int w    = tid >> 6;        // wave id 0..3 -> rows 16w..16w+15
    const int cg   = tid & 31;
    const int rg   = tid >> 5;
    const int c0   = cg * 4;
    const long r0  = (long)blockIdx.x * 64;

    // ---- W1 fragments -> VGPRs (L2-resident, identical across waves) ----
    const bf16x8* Wg1 = (const bf16x8*)Wt1;
    bf16x8 wf[8][4];
#pragma unroll
    for (int ct = 0; ct < 8; ++ct)
#pragma unroll
        for (int ks = 0; ks < 4; ++ks)
            wf[ct][ks] = Wg1[(ct * 4 + ks) * 64 + lane];

    // ---- stage X as bf16 hi/lo into swizzled LDS ----
#pragma unroll
    for (int p = 0; p < 8; ++p) {
        const int  row  = p * 8 + rg;
        const long grow = r0 + row;
        float4 v = make_float4(0.f, 0.f, 0.f, 0.f);
        if (MODE == 0) {
            const int sN = src[grow];
            const int dN = dst[grow];
            const float4 ev = *(const float4*)(e_or_agg + (size_t)grow * D + c0);
            const float4 hs = *(const float4*)(h + (size_t)sN * D + c0);
            const float4 hd = *(const float4*)(h + (size_t)dN * D + c0);
            v.x = ev.x + hs.x + hd.x; v.y = ev.y + hs.y + hd.y;
            v.z = ev.z + hs.z + hd.z; v.w = ev.w + hs.w + hd.w;
        } else {
            if (grow < NN) {
                const float4 hv = *(const float4*)(h + (size_t)grow * D + c0);
                const float4 av = *(const float4*)(e_or_agg + (size_t)grow * D + c0);
                v.x = hv.x + av.x; v.y = hv.y + av.y;
                v.z = hv.z + av.z; v.w = hv.w + av.w;
            }
        }
        us4 hi, lo;
        hi.x = f2bf(v.x); lo.x = f2bf(v.x - bf2f(hi.x));
        hi.y = f2bf(v.y); lo.y = f2bf(v.y - bf2f(hi.y));
        hi.z = f2bf(v.z); lo.z = f2bf(v.z - bf2f(hi.z));
        hi.w = f2bf(v.w); lo.w = f2bf(v.w - bf2f(hi.w));
        const int addr = row * 128 + (((c0 >> 3) ^ (row & 7)) << 3) + (c0 & 7);
        *(us4*)&Xh[addr] = hi;
        *(us4*)&Xl[addr] = lo;
    }
    __syncthreads();

    // ---- GEMM1 ----
    const int arow = 16 * w + (lane & 15);
    bf16x8 ah[4], al[4];
#pragma unroll
    for (int ks = 0; ks < 4; ++ks) {
        const int col0  = 32 * ks + ((lane >> 4) << 3);
        const int aaddr = arow * 128 + (((col0 >> 3) ^ (arow & 7)) << 3);
        ah[ks] = *(const bf16x8*)&Xh[aaddr];
        al[ks] = *(const bf16x8*)&Xl[aaddr];
    }
    f32x4 acc[8];
#pragma unroll
    for (int ct = 0; ct < 8; ++ct) acc[ct] = (f32x4){0.f, 0.f, 0.f, 0.f};
#pragma unroll
    for (int ct = 0; ct < 8; ++ct)
#pragma unroll
        for (int ks = 0; ks < 4; ++ks) {
            acc[ct] = __builtin_amdgcn_mfma_f32_16x16x32_bf16(ah[ks], wf[ct][ks], acc[ct], 0, 0, 0);
            acc[ct] = __builtin_amdgcn_mfma_f32_16x16x32_bf16(al[ks], wf[ct][ks], acc[ct], 0, 0, 0);
        }

    // ---- issue W2 loads (overwrite wf; latency hides under epilogue) ----
    const bf16x8* Wg2 = (const bf16x8*)Wt2;
#pragma unroll
    for (int ct = 0; ct < 8; ++ct)
#pragma unroll
        for (int ks = 0; ks < 4; ++ks)
            wf[ct][ks] = Wg2[(ct * 4 + ks) * 64 + lane];

    // ---- epilogue1: bias + relu -> f32 transpose buffer ----
#pragma unroll
    for (int ct = 0; ct < 8; ++ct) {
        const float b1c = b1[16 * ct + (lane & 15)];
#pragma unroll
        for (int r = 0; r < 4; ++r) {
            const int row = 16 * w + ((lane >> 4) << 2) + r;
            OUTB[row * 132 + 16 * ct + (lane & 15)] = fmaxf(acc[ct][r] + b1c, 0.f);
        }
    }
    __syncthreads();

    // ---- restage Y as bf16 hi/lo (row-major read, swizzled LDS write) ----
#pragma unroll
    for (int p = 0; p < 8; ++p) {
        const int row = p * 8 + rg;
        const float4 v = *(const float4*)&OUTB[row * 132 + c0];
        us4 hi, lo;
        hi.x = f2bf(v.x); lo.x = f2bf(v.x - bf2f(hi.x));
        hi.y = f2bf(v.y); lo.y = f2bf(v.y - bf2f(hi.y));
        hi.z = f2bf(v.z); lo.z = f2bf(v.z - bf2f(hi.z));
        hi.w = f2bf(v.w); lo.w = f2bf(v.w - bf2f(hi.w));
        const int addr = row * 128 + (((c0 >> 3) ^ (row & 7)) << 3) + (c0 & 7);
        *(us4*)&Xh[addr] = hi;
        *(us4*)&Xl[addr] = lo;
    }
    __syncthreads();

    // ---- GEMM2 ----
#pragma unroll
    for (int ks = 0; ks < 4; ++ks) {
        const int col0  = 32 * ks + ((lane >> 4) << 3);
        const int aaddr = arow * 128 + (((col0 >> 3) ^ (arow & 7)) << 3);
        ah[ks] = *(const bf16x8*)&Xh[aaddr];
        al[ks] = *(const bf16x8*)&Xl[aaddr];
    }
    f32x4 a2[8];
#pragma unroll
    for (int ct = 0; ct < 8; ++ct) a2[ct] = (f32x4){0.f, 0.f, 0.f, 0.f};
#pragma unroll
    for (int ct = 0; ct < 8; ++ct)
#pragma unroll
        for (int ks = 0; ks < 4; ++ks) {
            a2[ct] = __builtin_amdgcn_mfma_f32_16x16x32_bf16(ah[ks], wf[ct][ks], a2[ct], 0, 0, 0);
            a2[ct] = __builtin_amdgcn_mfma_f32_16x16x32_bf16(al[ks], wf[ct][ks], a2[ct], 0, 0, 0);
        }

    // ---- epilogue2: bias -> f32 transpose buffer ----
#pragma unroll
    for (int ct = 0; ct < 8; ++ct) {
        const float b2c = b2[16 * ct + (lane & 15)];
#pragma unroll
        for (int r = 0; r < 4; ++r) {
            const int row = 16 * w + ((lane >> 4) << 2) + r;
            OUTB[row * 132 + 16 * ct + (lane & 15)] = a2[ct][r] + b2c;
        }
    }
    __syncthreads();

    // ---- coalesced store + BN stats partials ----
    float ts[4] = {0.f, 0.f, 0.f, 0.f};
    float tq[4] = {0.f, 0.f, 0.f, 0.f};
#pragma unroll
    for (int p = 0; p < 8; ++p) {
        const int  row  = p * 8 + rg;
        const long grow = r0 + row;
        if (MODE == 1 && grow >= NN) continue;
        const float4 v = *(const float4*)&OUTB[row * 132 + c0];
        *(float4*)(x2out + (size_t)grow * D + c0) = v;
        ts[0] += v.x; ts[1] += v.y; ts[2] += v.z; ts[3] += v.w;
        tq[0] += v.x * v.x; tq[1] += v.y * v.y;
        tq[2] += v.z * v.z; tq[3] += v.w * v.w;
    }

    float* red = (float*)Xh;   // 4096 floats, Xh/Xl fully consumed
    *(float4*)&red[rg * 128 + c0]        = make_float4(ts[0], ts[1], ts[2], ts[3]);
    *(float4*)&red[2048 + rg * 128 + c0] = make_float4(tq[0], tq[1], tq[2], tq[3]);
    __syncthreads();
    if (tid < 128) {
        float s = 0.f, q = 0.f;
#pragma unroll
        for (int g = 0; g < 8; ++g) {
            s += red[g * 128 + tid];
            q += red[2048 + g * 128 + tid];
        }
        unsafeAtomicAdd(&stats[tid], s);
        unsafeAtomicAdd(&stats[128 + tid], q);
    }
}

// stats layout: [0:128) sum, [128:256) sumsq, [256:384) scale, [384:512) shift
__global__ void bn_finalize_kernel(float* __restrict__ stats,
                                   const float* __restrict__ gamma,
                                   const float* __restrict__ beta,
                                   float inv_count)
{
    const int c = threadIdx.x;
    if (c < D) {
        const float mu  = stats[c] * inv_count;
        const float var = stats[128 + c] * inv_count - mu * mu;
        const float sc  = rsqrtf(var + BN_EPS) * gamma[c];
        stats[256 + c] = sc;
        stats[384 + c] = beta[c] - mu * sc;
    }
}

// ---- CSR build ----
__global__ __launch_bounds__(256) void hist_kernel(
    const int* __restrict__ dst, int* __restrict__ cnt)
{
    const int i = blockIdx.x * 256 + threadIdx.x;
    if (i < NE) atomicAdd(&cnt[dst[i]], 1);
}

__global__ __launch_bounds__(1024) void scan_kernel(
    const int* __restrict__ cnt, int* __restrict__ off)
{
    __shared__ int part[1024];
    const int t = threadIdx.x;
    const int SEG = (NN + 1023) / 1024;
    const int base = t * SEG;

    int s = 0;
    for (int i = 0; i < SEG; ++i) {
        const int idx = base + i;
        if (idx < NN) s += cnt[idx];
    }
    part[t] = s;
    __syncthreads();
    for (int d = 1; d < 1024; d <<= 1) {
        int v = (t >= d) ? part[t - d] : 0;
        __syncthreads();
        part[t] += v;
        __syncthreads();
    }
    int run = (t > 0) ? part[t - 1] : 0;
    for (int i = 0; i < SEG; ++i) {
        const int idx = base + i;
        if (idx < NN) { off[idx] = run; run += cnt[idx]; }
    }
    if (t == 1023) off[NN] = part[1023];
}

__global__ __launch_bounds__(256) void csr_scatter_kernel(
    const int* __restrict__ dst, const int* __restrict__ off,
    int* __restrict__ cnt, int* __restrict__ csr)
{
    const int i = blockIdx.x * 256 + threadIdx.x;
    if (i < NE) {
        const int d = dst[i];
        const int p = atomicSub(&cnt[d], 1) - 1;
        csr[off[d] + p] = i;
    }
}

// ---------------------------------------------------------------------------
// Fused BN-apply + residual + segment-sum gather. One wave per node walks its
// CSR edge list: e_new = x2*sc + sh + e written in place over x2 (each edge
// row owned by exactly one node), agg accumulated in registers.
// ---------------------------------------------------------------------------
__global__ __launch_bounds__(256) void apply_gather_kernel(
    const float* __restrict__ e, const float* __restrict__ stats,
    const int* __restrict__ off, const int* __restrict__ csr,
    float* __restrict__ eout, float* __restrict__ agg)
{
    const int node = blockIdx.x * 4 + (threadIdx.x >> 6);
    const int lane = threadIdx.x & 63;
    const int c0   = lane * 2;
    if (node >= NN) return;

    const float2 sc = *(const float2*)(stats + 256 + c0);
    const float2 sh = *(const float2*)(stats + 384 + c0);
    float2 acc = make_float2(0.f, 0.f);
    const int jb = off[node], je = off[node + 1];
    for (int j = jb; j < je; ++j) {
        const int eidx = csr[j];
        const size_t base = (size_t)eidx * D + c0;
        const float2 x  = *(const float2*)(eout + base);
        const float2 ev = *(const float2*)(e + base);
        float2 v;
        v.x = fmaf(x.x, sc.x, sh.x) + ev.x;
        v.y = fmaf(x.y, sc.y, sh.y) + ev.y;
        *(float2*)(eout + base) = v;
        acc.x += v.x;
        acc.y += v.y;
    }
    *(float2*)(agg + (size_t)node * D + c0) = acc;
}

// h_new = y2*scale + shift + h (in-place over y2 in d_out)
__global__ __launch_bounds__(256) void node_apply_kernel(
    const float* __restrict__ h, const float* __restrict__ stats,
    float* __restrict__ hout)
{
    const int gid = blockIdx.x * 256 + threadIdx.x;
    const int c0  = (gid & 31) * 4;
    const size_t base = (size_t)(gid >> 5) * D + c0;

    const float4 sc = *(const float4*)(stats + 256 + c0);
    const float4 sh = *(const float4*)(stats + 384 + c0);
    const float4 x  = *(const float4*)(hout + base);
    const float4 hv = *(const float4*)(h + base);
    float4 v;
    v.x = fmaf(x.x, sc.x, sh.x) + hv.x;
    v.y = fmaf(x.y, sc.y, sh.y) + hv.y;
    v.z = fmaf(x.z, sc.z, sh.z) + hv.z;
    v.w = fmaf(x.w, sc.w, sh.w) + hv.w;
    *(float4*)(hout + base) = v;
}

extern "C" void kernel_launch(void* const* d_in, const int* in_sizes, int n_in,
                              void* d_out, int out_size, void* d_ws, size_t ws_size,
                              hipStream_t stream)
{
    const float* h   = (const float*)d_in[0];
    const float* e   = (const float*)d_in[1];
    const int*   src = (const int*)d_in[2];
    const int*   dst = (const int*)d_in[3];
    const float* Wa1 = (const float*)d_in[4];
    const float* ba1 = (const float*)d_in[5];
    const float* Wa2 = (const float*)d_in[6];
    const float* ba2 = (const float*)d_in[7];
    const float* Wb1 = (const float*)d_in[8];
    const float* bb1 = (const float*)d_in[9];
    const float* Wb2 = (const float*)d_in[10];
    const float* bb2 = (const float*)d_in[11];
    const float* ga  = (const float*)d_in[12];
    const float* bea = (const float*)d_in[13];
    const float* gb  = (const float*)d_in[14];
    const float* beb = (const float*)d_in[15];

    float* out  = (float*)d_out;
    float* hnew = out;                      // NN*D
    float* enew = out + (size_t)NN * D;     // NE*D (x2 scratch, then e_new)

    // ws layout (float units):
    //   estats[512] | nstats[512] | icnt[NN ints] | ioff[NN+1 ints] | pad3 |
    //   Wtb1/Wtb2/Wta1/Wta2 (4 x 16384 ushort = 4 x 8192 f) | csr[NE ints] | agg[NN*D]
    float* ws     = (float*)d_ws;
    float* estats = ws;
    float* nstats = ws + 512;
    int*   icnt   = (int*)(ws + 1024);
    int*   ioff   = icnt + NN;
    unsigned short* wtb1 = (unsigned short*)(ioff + NN + 1 + 3);  // 16B aligned
    unsigned short* wtb2 = wtb1 + 16384;
    unsigned short* wta1 = wtb2 + 16384;
    unsigned short* wta2 = wta1 + 16384;
    int*   icsr  = (int*)(wta2 + 16384);
    float* agg   = (float*)(icsr + NE);

    // zero BN stats + histogram counters
    hipMemsetAsync(d_ws, 0, (size_t)(1024 + NN) * sizeof(float), stream);

    // ---- weight prep (fragment-linear bf16) ----
    wprep_kernel<<<64, 256, 0, stream>>>(Wb1, wtb1);
    wprep_kernel<<<64, 256, 0, stream>>>(Wb2, wtb2);
    wprep_kernel<<<64, 256, 0, stream>>>(Wa1, wta1);
    wprep_kernel<<<64, 256, 0, stream>>>(Wa2, wta2);

    // ---- CSR build ----
    hist_kernel<<<(NE + 255) / 256, 256, 0, stream>>>(dst, icnt);
    scan_kernel<<<1, 1024, 0, stream>>>(icnt, ioff);
    csr_scatter_kernel<<<(NE + 255) / 256, 256, 0, stream>>>(dst, ioff, icnt, icsr);

    // ---- bond (edge) path ----
    mlp_mfma_kernel<0><<<NE / 64, 256, 0, stream>>>(h, e, src, dst,
                                                    wtb1, bb1, wtb2, bb2,
                                                    enew /*x2*/, estats);
    bn_finalize_kernel<<<1, 128, 0, stream>>>(estats, gb, beb, 1.0f / NE);
    apply_gather_kernel<<<(NN + 3) / 4, 256, 0, stream>>>(e, estats, ioff, icsr,
                                                          enew, agg);

    // ---- atom (node) path ----
    mlp_mfma_kernel<1><<<(NN + 63) / 64, 256, 0, stream>>>(h, agg, nullptr, nullptr,
                                                           wta1, ba1, wta2, ba2,
                                                           hnew /*y2*/, nstats);
    bn_finalize_kernel<<<1, 128, 0, stream>>>(nstats, ga, bea, 1.0f / NN);
    node_apply_kernel<<<(NN * 32) / 256, 256, 0, stream>>>(h, nstats, hnew);
}